// Round 3
// baseline (94.678 us; speedup 1.0000x reference)
//
#include <hip/hip_runtime.h>
#include <hip/hip_bf16.h>
#include <math.h>

// S4D: out[h,l] = 2*Re( sum_n Cc'[h,n] * exp(dtA[h,n]*l) ), H=1024, N2=32, L=4096.
// Per-block h; thread t owns l = t + 256*j (coalesced stores). Geometric
// recurrence S <- S*R with R = exp(dtA*256).
// KEY: R is block-uniform -> held in SGPRs via readfirstlane (64 SGPRs), so
// per-thread VGPR state is only Sre+Sim = 64 regs -> 4 waves/SIMD, no spills.
// Each scalar VALU op reads at most 1 SGPR (VOP3-legal), neg via input modifier.

constexpr int H_  = 1024;
constexpr int N2_ = 32;
constexpr int L_  = 4096;
constexpr int BT_ = 256;          // threads per block
constexpr int NJ_ = L_ / BT_;     // 16 l-values per thread

__device__ __forceinline__ float rfl(float x) {
    return __int_as_float(__builtin_amdgcn_readfirstlane(__float_as_int(x)));
}

__global__ __launch_bounds__(BT_) void s4d_kernel(
    const float* __restrict__ log_dt,
    const float* __restrict__ C,
    const float* __restrict__ log_A_real,
    const float* __restrict__ A_imag,
    float* __restrict__ out)
{
    __shared__ float sCre[N2_], sCim[N2_];  // Cc' = Cc*(e^{dtA}-1)/A
    __shared__ float sRre[N2_], sRim[N2_];  // R = exp(dtA*256)
    __shared__ float sAl2[N2_];             // dtA_re * log2(e)
    __shared__ float sRho[N2_];             // fract(dtA_im/2pi), rev/step

    const int h = blockIdx.x;
    const int t = threadIdx.x;

    if (t < N2_) {
        const int n = t;
        const float L2E = 1.442695040888963f;
        const float dt   = __builtin_amdgcn_exp2f(log_dt[h] * L2E);
        const float ar   = -__builtin_amdgcn_exp2f(log_A_real[h * N2_ + n] * L2E);
        const float ai   = A_imag[h * N2_ + n];
        const float dtar = ar * dt;
        const float dtai = ai * dt;
        const float INV2PI = 0.15915494309189535f;

        // Cc' = Cc * (e^{dtA}-1) / A   (fp32 throughout; |dtai|<~10 rad ok)
        const float em  = __builtin_amdgcn_exp2f(dtar * L2E);
        float efr = dtai * INV2PI; efr -= floorf(efr);
        const float ere = em * __builtin_amdgcn_cosf(efr) - 1.0f;
        const float eim = em * __builtin_amdgcn_sinf(efr);
        const float cre = C[(h * N2_ + n) * 2 + 0];
        const float cim = C[(h * N2_ + n) * 2 + 1];
        const float inv = 1.0f / (ar * ar + ai * ai);
        const float qre = (ere * ar + eim * ai) * inv;
        const float qim = (eim * ar - ere * ai) * inv;
        sCre[n] = cre * qre - cim * qim;
        sCim[n] = cre * qim + cim * qre;

        sAl2[n] = dtar * L2E;

        // phase reductions: fp64 only here (rho*256 can be ~400 revolutions)
        const double rho = (double)dtai * 0.15915494309189535;
        sRho[n] = (float)(rho - floor(rho));
        double prv = rho * 256.0;
        prv -= floor(prv);
        const float prf  = (float)prv;
        const float rmag = __builtin_amdgcn_exp2f(dtar * (256.0f * L2E));
        sRre[n] = rmag * __builtin_amdgcn_cosf(prf);
        sRim[n] = rmag * __builtin_amdgcn_sinf(prf);
    }
    __syncthreads();

    // Hoist block-uniform R into SGPRs (64 scalar regs).
    float Rre[N2_], Rim[N2_];
    #pragma unroll
    for (int n = 0; n < N2_; n++) {
        Rre[n] = rfl(sRre[n]);
        Rim[n] = rfl(sRim[n]);
    }

    float Sre[N2_], Sim[N2_];
    const float tf = (float)t;
    float a0 = 0.f, a1 = 0.f, a2 = 0.f, a3 = 0.f;

    // init: S_n = Cc'_n * exp(dtA_n * t)
    #pragma unroll
    for (int n = 0; n < N2_; n++) {
        const float mag = __builtin_amdgcn_exp2f(sAl2[n] * tf);
        const float ph  = sRho[n] * tf;
        const float fr  = ph - floorf(ph);
        const float s   = __builtin_amdgcn_sinf(fr);
        const float c   = __builtin_amdgcn_cosf(fr);
        const float cr  = sCre[n], ci = sCim[n];
        const float re  = mag * (cr * c - ci * s);
        Sre[n] = re;
        Sim[n] = mag * (cr * s + ci * c);
        if ((n & 3) == 0) a0 += re; else if ((n & 3) == 1) a1 += re;
        else if ((n & 3) == 2) a2 += re; else a3 += re;
    }

    float* op = out + (size_t)h * L_ + t;
    op[0] = 2.f * ((a0 + a1) + (a2 + a3));

    // recurrence: S <- S*R advances l by 256.
    // Per mode: v_mul(v,s), v_mul(v,s), v_fma(v,-s,v), v_fma(v,s,v), v_add.
    #pragma unroll 1
    for (int j = 1; j < NJ_; j++) {
        a0 = 0.f; a1 = 0.f; a2 = 0.f; a3 = 0.f;
        #pragma unroll
        for (int n = 0; n < N2_; n++) {
            const float t0  = Sre[n] * Rre[n];
            const float t1  = Sre[n] * Rim[n];
            const float nre = __builtin_fmaf(Sim[n], -Rim[n], t0);
            const float nim = __builtin_fmaf(Sim[n],  Rre[n], t1);
            Sre[n] = nre;
            Sim[n] = nim;
            if ((n & 3) == 0) a0 += nre; else if ((n & 3) == 1) a1 += nre;
            else if ((n & 3) == 2) a2 += nre; else a3 += nre;
        }
        op[j * BT_] = 2.f * ((a0 + a1) + (a2 + a3));
    }
}

extern "C" void kernel_launch(void* const* d_in, const int* in_sizes, int n_in,
                              void* d_out, int out_size, void* d_ws, size_t ws_size,
                              hipStream_t stream) {
    const float* log_dt     = (const float*)d_in[1];
    const float* C          = (const float*)d_in[2];
    const float* log_A_real = (const float*)d_in[3];
    const float* A_imag     = (const float*)d_in[4];
    float* out = (float*)d_out;

    s4d_kernel<<<dim3(H_), dim3(BT_), 0, stream>>>(log_dt, C, log_A_real, A_imag, out);
}

// Round 4
// 70.032 us; speedup vs baseline: 1.3519x; 1.3519x over previous
//
#include <hip/hip_runtime.h>
#include <hip/hip_bf16.h>
#include <math.h>

// S4D as batched GEMM.  out[h, i*64+j] = 2*Re( sum_n Cc'[h,n] * W[h,n]^i * q[h,n]^j )
// with W = exp(dtA*64), q = exp(dtA).  Per h this is a real 64x64x64 matmul:
//   A[i][k]  : k=n -> Re(Cc'*W^i), k=32+n -> -Im(Cc'*W^i)      (64 x 64)
//   B[k][j]  : k=n -> Re(q^j),     k=32+n ->  Im(q^j)           (64 x 64)
//   out_tile = 2 * A*B
// Done in MFMA 16x16x32 bf16 with hi/lo split (Ah*Bh + Ah*Bl + Al*Bh): rel err
// ~2^-16, abs err ~2e-4 << 3.06e-2 threshold.  One block per h, 4 waves; each
// wave owns a 16-row band of the 64x64 output (4 n-tiles, K=64 -> 2 k-steps,
// x3 splits = 24 MFMA/wave).  B stored transposed (Bt[j][k]) so both operand
// fragments are 8 contiguous bf16 -> ds_read_b128.  K-stride padded to 72
// (144 B, 16B-aligned, 2-way banks = free).

typedef __bf16 bf16x4 __attribute__((ext_vector_type(4)));
typedef __bf16 bf16x8 __attribute__((ext_vector_type(8)));
typedef float  f32x4  __attribute__((ext_vector_type(4)));

constexpr int H_  = 1024;
constexpr int N2_ = 32;
constexpr int L_  = 4096;
constexpr int BT_ = 256;
constexpr int KP_ = 72;   // padded K stride in bf16 elems

__global__ __launch_bounds__(BT_) void s4d_kernel(
    const float* __restrict__ log_dt,
    const float* __restrict__ C,
    const float* __restrict__ log_A_real,
    const float* __restrict__ A_imag,
    float* __restrict__ out)
{
    __shared__ __bf16 Ah[64][KP_], Al[64][KP_];   // A hi/lo   (i  x k)
    __shared__ __bf16 Bh[64][KP_], Bl[64][KP_];   // B^T hi/lo (j  x k)
    __shared__ float sCre[N2_], sCim[N2_];        // Cc'
    __shared__ float sAl2[N2_];                   // dtar*log2e      (per-step mag)
    __shared__ float sRho1[N2_];                  // fract(dtai/2pi) (per-step phase)
    __shared__ float sM64[N2_];                   // dtar*64*log2e   (per-64-step mag)
    __shared__ float sRho64[N2_];                 // fract(64*dtai/2pi)

    const int h = blockIdx.x;
    const int t = threadIdx.x;
    const float L2E = 1.442695040888963f;

    if (t < N2_) {
        const int n = t;
        const float dt   = __builtin_amdgcn_exp2f(log_dt[h] * L2E);
        const float ar   = -__builtin_amdgcn_exp2f(log_A_real[h * N2_ + n] * L2E);
        const float ai   = A_imag[h * N2_ + n];
        const float dtar = ar * dt;
        const float dtai = ai * dt;

        // Cc' = Cc * (e^{dtA}-1)/A
        const float em  = __builtin_amdgcn_exp2f(dtar * L2E);
        float efr = dtai * 0.15915494309189535f; efr -= floorf(efr);
        const float ere = em * __builtin_amdgcn_cosf(efr) - 1.0f;
        const float eim = em * __builtin_amdgcn_sinf(efr);
        const float cre = C[(h * N2_ + n) * 2 + 0];
        const float cim = C[(h * N2_ + n) * 2 + 1];
        const float inv = 1.0f / (ar * ar + ai * ai);
        const float qre = (ere * ar + eim * ai) * inv;
        const float qim = (eim * ar - ere * ai) * inv;
        sCre[n] = cre * qre - cim * qim;
        sCim[n] = cre * qim + cim * qre;

        sAl2[n] = dtar * L2E;
        sM64[n] = dtar * (64.0f * L2E);
        // phase reductions mod 1 revolution in fp64 (only place fp64 is needed)
        const double rho = (double)dtai * 0.15915494309189535;
        sRho1[n]  = (float)(rho - floor(rho));
        const double r64 = rho * 64.0;
        sRho64[n] = (float)(r64 - floor(r64));
    }
    __syncthreads();

    // ---- generate A (row = i) and B^T (row = j), 8 modes per thread ----
    {
        const int row = t >> 2;          // 0..63 : i for A, j for B
        const int n0  = (t & 3) * 8;     // modes n0..n0+7
        const float rf = (float)row;
        __bf16 hRe[8], lRe[8], hIm[8], lIm[8];
        __bf16 gRe[8], mRe[8], gIm[8], mIm[8];

        #pragma unroll
        for (int qi = 0; qi < 8; qi++) {
            const int n = n0 + qi;
            // A: Cc' * W^row
            {
                const float mag = __builtin_amdgcn_exp2f(sM64[n] * rf);
                float ph = sRho64[n] * rf; ph -= floorf(ph);
                const float c = __builtin_amdgcn_cosf(ph);
                const float s = __builtin_amdgcn_sinf(ph);
                const float wre = mag * c, wim = mag * s;
                const float are = sCre[n] * wre - sCim[n] * wim;
                const float aim = sCre[n] * wim + sCim[n] * wre;
                const float nim = -aim;
                const __bf16 h1 = (__bf16)are; hRe[qi] = h1; lRe[qi] = (__bf16)(are - (float)h1);
                const __bf16 h2 = (__bf16)nim; hIm[qi] = h2; lIm[qi] = (__bf16)(nim - (float)h2);
            }
            // B: q^row
            {
                const float mag = __builtin_amdgcn_exp2f(sAl2[n] * rf);
                float ph = sRho1[n] * rf; ph -= floorf(ph);
                const float c = __builtin_amdgcn_cosf(ph);
                const float s = __builtin_amdgcn_sinf(ph);
                const float bre = mag * c, bim = mag * s;
                const __bf16 h1 = (__bf16)bre; gRe[qi] = h1; mRe[qi] = (__bf16)(bre - (float)h1);
                const __bf16 h2 = (__bf16)bim; gIm[qi] = h2; mIm[qi] = (__bf16)(bim - (float)h2);
            }
        }
        *(bf16x4*)&Ah[row][n0]        = (bf16x4){hRe[0], hRe[1], hRe[2], hRe[3]};
        *(bf16x4*)&Ah[row][n0 + 4]    = (bf16x4){hRe[4], hRe[5], hRe[6], hRe[7]};
        *(bf16x4*)&Ah[row][32 + n0]   = (bf16x4){hIm[0], hIm[1], hIm[2], hIm[3]};
        *(bf16x4*)&Ah[row][36 + n0]   = (bf16x4){hIm[4], hIm[5], hIm[6], hIm[7]};
        *(bf16x4*)&Al[row][n0]        = (bf16x4){lRe[0], lRe[1], lRe[2], lRe[3]};
        *(bf16x4*)&Al[row][n0 + 4]    = (bf16x4){lRe[4], lRe[5], lRe[6], lRe[7]};
        *(bf16x4*)&Al[row][32 + n0]   = (bf16x4){lIm[0], lIm[1], lIm[2], lIm[3]};
        *(bf16x4*)&Al[row][36 + n0]   = (bf16x4){lIm[4], lIm[5], lIm[6], lIm[7]};
        *(bf16x4*)&Bh[row][n0]        = (bf16x4){gRe[0], gRe[1], gRe[2], gRe[3]};
        *(bf16x4*)&Bh[row][n0 + 4]    = (bf16x4){gRe[4], gRe[5], gRe[6], gRe[7]};
        *(bf16x4*)&Bh[row][32 + n0]   = (bf16x4){gIm[0], gIm[1], gIm[2], gIm[3]};
        *(bf16x4*)&Bh[row][36 + n0]   = (bf16x4){gIm[4], gIm[5], gIm[6], gIm[7]};
        *(bf16x4*)&Bl[row][n0]        = (bf16x4){mRe[0], mRe[1], mRe[2], mRe[3]};
        *(bf16x4*)&Bl[row][n0 + 4]    = (bf16x4){mRe[4], mRe[5], mRe[6], mRe[7]};
        *(bf16x4*)&Bl[row][32 + n0]   = (bf16x4){mIm[0], mIm[1], mIm[2], mIm[3]};
        *(bf16x4*)&Bl[row][36 + n0]   = (bf16x4){mIm[4], mIm[5], mIm[6], mIm[7]};
    }
    __syncthreads();

    // ---- MFMA: wave w owns rows [16w, 16w+16) of the 64x64 tile ----
    const int wv   = t >> 6;
    const int lid  = t & 63;
    const int lo16 = lid & 15;
    const int q4   = lid >> 4;
    const int mrow = wv * 16 + lo16;

    f32x4 acc[4] = {f32x4{0,0,0,0}, f32x4{0,0,0,0}, f32x4{0,0,0,0}, f32x4{0,0,0,0}};

    #pragma unroll
    for (int kt = 0; kt < 2; kt++) {
        const int kk = kt * 32 + q4 * 8;
        const bf16x8 af = *(const bf16x8*)&Ah[mrow][kk];
        const bf16x8 al = *(const bf16x8*)&Al[mrow][kk];
        #pragma unroll
        for (int nt = 0; nt < 4; nt++) {
            const bf16x8 bf = *(const bf16x8*)&Bh[nt * 16 + lo16][kk];
            const bf16x8 bl = *(const bf16x8*)&Bl[nt * 16 + lo16][kk];
            acc[nt] = __builtin_amdgcn_mfma_f32_16x16x32_bf16(af, bf, acc[nt], 0, 0, 0);
            acc[nt] = __builtin_amdgcn_mfma_f32_16x16x32_bf16(af, bl, acc[nt], 0, 0, 0);
            acc[nt] = __builtin_amdgcn_mfma_f32_16x16x32_bf16(al, bf, acc[nt], 0, 0, 0);
        }
    }

    // ---- epilogue: D[row=(q4*4+r)][col=lo16] per tile; l = i*64 + j ----
    float* op = out + (size_t)h * L_;
    #pragma unroll
    for (int nt = 0; nt < 4; nt++) {
        const int j = nt * 16 + lo16;
        #pragma unroll
        for (int r = 0; r < 4; r++) {
            const int i = wv * 16 + q4 * 4 + r;
            op[i * 64 + j] = 2.0f * acc[nt][r];
        }
    }
}

extern "C" void kernel_launch(void* const* d_in, const int* in_sizes, int n_in,
                              void* d_out, int out_size, void* d_ws, size_t ws_size,
                              hipStream_t stream) {
    const float* log_dt     = (const float*)d_in[1];
    const float* C          = (const float*)d_in[2];
    const float* log_A_real = (const float*)d_in[3];
    const float* A_imag     = (const float*)d_in[4];
    float* out = (float*)d_out;
    (void)d_ws; (void)ws_size;

    s4d_kernel<<<dim3(H_), dim3(BT_), 0, stream>>>(log_dt, C, log_A_real, A_imag, out);
}